// Round 20
// baseline (248.347 us; speedup 1.0000x reference)
//
#include <hip/hip_runtime.h>
#include <hip/hip_bf16.h>
#include <cstdint>
#include <cstddef>

#define BQ 128        // queries (problem-fixed)
#define DK 192        // SIG_DIM
#define KTOP 32
#define CHI 32        // gallery items per chunk
#define NSH 64        // candidate shards per query (contention spread)
#define SCAP 256      // slots per (query, shard)
#define LCCAP 2048    // select: collect buffer
#define OCAP 65536    // global overflow list
#define MARGIN 0.02f  // > 2x bf16 dot error bound (~0.012)
#define SCN 768       // sampled chunks for threshold
#define THRV 3200     // thr32 LDS value slots
#define GRID1 768     // filter-pass blocks (3/CU)

#define NEG_INF (-__builtin_huge_valf())

typedef short short8v __attribute__((ext_vector_type(8)));
typedef float f32x16  __attribute__((ext_vector_type(16)));

__device__ __forceinline__ unsigned fkey(float s) {
    unsigned u = __float_as_uint(s);
    return (u & 0x80000000u) ? ~u : (u | 0x80000000u);   // monotone f32 -> u32
}
__device__ __forceinline__ float keyval(unsigned k) {    // inverse of fkey
    return (k & 0x80000000u) ? __uint_as_float(k & 0x7FFFFFFFu)
                             : __uint_as_float(~k);
}
__device__ __forceinline__ bool pri_gt(float s1, int i1, float s2, int i2) {
    return (s1 > s2) || (s1 == s2 && i1 < i2);           // jax top_k stability
}
__device__ __forceinline__ unsigned pk_trunc(float a, float b) {
    return __builtin_amdgcn_perm(__float_as_uint(b), __float_as_uint(a),
                                 0x07060302u);
}
__device__ __forceinline__ unsigned f2bf_rne(float x) {
    unsigned u = __float_as_uint(x);
    unsigned r = u + 0x7FFFu + ((u >> 16) & 1u);
    return r >> 16;
}
__device__ __forceinline__ float dot192(const float* __restrict__ a,
                                        const float* __restrict__ b) {
    float s = 0.f;
    #pragma unroll 8
    for (int k = 0; k < DK; ++k) s = fmaf(a[k], b[k], s);
    return s;
}
__device__ __forceinline__ void gload_lds16(const void* g, void* l) {
    __builtin_amdgcn_global_load_lds(
        (const __attribute__((address_space(1))) unsigned int*)g,
        (__attribute__((address_space(3))) unsigned int*)l,
        16, 0, 0);
}

// ---------------------------------------------------------------------------
// qprep: Q image FRAGMENT-ORDERED (48 KB), r18-verified mapping.
// ---------------------------------------------------------------------------
__global__ __launch_bounds__(256) void qprep(
    const float* __restrict__ Qf, unsigned short* __restrict__ Qi)
{
    const int b = blockIdx.x * 256 + threadIdx.x;
    if (b >= 12 * 256) return;
    const int s = b >> 8, w = (b >> 6) & 3, lane = b & 63;
    const int q  = w * 32 + (lane & 31);
    const int k0 = (lane >> 5) * 8 + s * 16;
    const float* qp = Qf + q * DK + k0;
    unsigned short* dst = Qi + (size_t)b * 8;
    #pragma unroll
    for (int e = 0; e < 8; ++e) dst[e] = (unsigned short)f2bf_rne(qp[e]);
}

// ---------------------------------------------------------------------------
// Multi-chunk MFMA scoring: FEW blocks (dispatch-rate floor was ~70 WG/us =>
// 6250 single-chunk blocks = the 89us invariant), each looping ~9 chunks.
// G: global_load_lds fp32 DOUBLE BUFFER (zero loop-carried load VGPRs),
// counted s_waitcnt vmcnt(6) + raw s_barrier => loads in flight across
// barriers (T3/T4 minimum pipeline). Q fragments pinned per iteration.
// MODE 0: masked per-(sample,q) bf16 max -> gmax[si][q]
// MODE 1: threshold filter -> mask probe -> sharded dense store (no rescore)
// ---------------------------------------------------------------------------
template<int MODE>
__global__ __launch_bounds__(256, 2) void score_pass(
    const unsigned short* __restrict__ Qi, const float* __restrict__ G,
    const int* __restrict__ mask, const float* __restrict__ thrm,
    float* __restrict__ gmax,
    int* __restrict__ gcnt, float* __restrict__ cs, int* __restrict__ ci,
    int* __restrict__ ocnt, int* __restrict__ oq, int* __restrict__ og,
    float* __restrict__ osv,
    int Ntot, int NCH, int SC)
{
    __shared__ float Gf[2][CHI * DK];      // 2 x 24 KB fp32 tiles
    __shared__ float thrmS[BQ];

    const int t = threadIdx.x;
    const int w = t >> 6, lane = t & 63;
    const int lo5 = lane & 31, hi = lane >> 5;
    const int qbW = w * 32;
    const int shard = blockIdx.x & (NSH - 1);

    // Q fragments: coalesced wave-loads from fragment image, pinned.
    uint4 aF[12];
    {
        const uint4* qp = reinterpret_cast<const uint4*>(Qi) + (w << 6) + lane;
        #pragma unroll
        for (int s = 0; s < 12; ++s) aF[s] = qp[s << 8];
    }
    #pragma unroll
    for (int s = 0; s < 12; ++s)
        asm volatile("" : "+v"(aF[s].x), "+v"(aF[s].y),
                          "+v"(aF[s].z), "+v"(aF[s].w));

    if (t < BQ) thrmS[t] = (MODE == 1) ? thrm[t] : 0.f;

    const int limit  = (MODE == 0) ? SC : NCH;
    const int stride = (int)gridDim.x;

    auto CHUNK_OF = [&](int si) {
        return (MODE == 0) ? (int)(((long long)si * NCH) / SC) : si;
    };
    auto ISSUE = [&](int chunk, int buf) {
        const size_t cbase = (size_t)chunk * CHI;
        #pragma unroll
        for (int i = 0; i < 6; ++i) {
            const int slot = t + (i << 8);
            const int r = slot / 48, c = slot - r * 48;
            size_t grow = cbase + r;
            if (grow >= (size_t)Ntot) grow = (size_t)Ntot - 1;
            const char* gp = (const char*)G + grow * (DK * 4)
                           + ((c ^ (r & 7)) << 4);
            char* lp = (char*)&Gf[buf][0] + ((i << 2) + w) * 1024;
            gload_lds16(gp, lp);
        }
    };

    int si = blockIdx.x;
    if (si < limit) ISSUE(CHUNK_OF(si), 0);
    __syncthreads();                       // thrmS visible (drains buf0 too, once)
    int cur = 0;

    const unsigned xsh = (unsigned)((lo5 & 7) << 4);

    while (si < limit) {
        const int chunk = CHUNK_OF(si);
        const int cb = chunk * CHI;
        const int nx = si + stride;
        const bool more = nx < limit;
        if (more) ISSUE(CHUNK_OF(nx), cur ^ 1);     // stays in flight

        if (more) asm volatile("s_waitcnt vmcnt(6)" ::: "memory");
        else      asm volatile("s_waitcnt vmcnt(0)" ::: "memory");
        __builtin_amdgcn_sched_barrier(0);
        __builtin_amdgcn_s_barrier();               // buf[cur] ready

        #pragma unroll
        for (int s = 0; s < 12; ++s)
            asm volatile("" : "+v"(aF[s].x), "+v"(aF[s].y),
                              "+v"(aF[s].z), "+v"(aF[s].w));  // keep resident

        const char* rowp = (const char*)&Gf[cur][0] + lo5 * (DK * 4);
        f32x16 acc = {0,0,0,0,0,0,0,0,0,0,0,0,0,0,0,0};
        #pragma unroll
        for (int s = 0; s < 12; ++s) {
            const unsigned b0 = ((unsigned)((s * 4 + hi * 2) << 4)) ^ xsh;
            const unsigned b1 = ((unsigned)((s * 4 + hi * 2 + 1) << 4)) ^ xsh;
            float4 f0 = *reinterpret_cast<const float4*>(rowp + b0);
            float4 f1 = *reinterpret_cast<const float4*>(rowp + b1);
            union { unsigned u[4]; short8v v; } bu;
            bu.u[0] = pk_trunc(f0.x, f0.y); bu.u[1] = pk_trunc(f0.z, f0.w);
            bu.u[2] = pk_trunc(f1.x, f1.y); bu.u[3] = pk_trunc(f1.z, f1.w);
            union { uint4 u; short8v v; } au; au.u = aF[s];
            acc = __builtin_amdgcn_mfma_f32_32x32x16_bf16(au.v, bu.v, acc, 0, 0, 0);
        }

        // D layout: row(query)=(j&3)+8*(j>>2)+4*hi (+qbW), col(item)=lane&31
        const int g = cb + lo5;
        if (MODE == 0) {
            #pragma unroll
            for (int j = 0; j < 16; ++j) {
                const int row = (j & 3) + 8 * (j >> 2) + 4 * hi;
                const int q = qbW + row;
                float m = NEG_INF;
                if (g < Ntot && !mask[(size_t)q * (size_t)Ntot + g])
                    m = acc[j];
                #pragma unroll
                for (int off = 1; off < 32; off <<= 1)
                    m = fmaxf(m, __shfl_xor(m, off));
                if (lo5 == 0) gmax[(size_t)si * BQ + q] = m;
            }
        } else {
            #pragma unroll
            for (int j = 0; j < 16; ++j) {
                const int row = (j & 3) + 8 * (j >> 2) + 4 * hi;
                const int q = qbW + row;
                const float s = acc[j];
                if (g < Ntot && s >= thrmS[q]) {
                    if (!mask[(size_t)q * (size_t)Ntot + g]) {
                        const int cidx = q * NSH + shard;
                        const int pos = atomicAdd(&gcnt[cidx * 16], 1);
                        if (pos < SCAP) {
                            const size_t o = (size_t)cidx * SCAP + pos;
                            cs[o] = s; ci[o] = g;
                        } else {
                            const int op = atomicAdd(ocnt, 1);
                            if (op < OCAP) { oq[op] = q; og[op] = g; osv[op] = s; }
                        }
                    }
                }
            }
        }
        __builtin_amdgcn_s_barrier();      // all reads of buf[cur] done
        cur ^= 1;
        si = nx;
    }
}

// ---------------------------------------------------------------------------
// thrm[q] = (exact 32nd-largest of SC sampled masked chunk-maxima) - MARGIN.
// ---------------------------------------------------------------------------
__global__ __launch_bounds__(256) void thr32(
    const float* __restrict__ gmax, float* __restrict__ thrm, int SC)
{
    __shared__ float vals[THRV];
    __shared__ int hist[256];
    __shared__ int hscan[256];
    __shared__ int bS, gtS;

    const int q = blockIdx.x;
    const int t = threadIdx.x;
    const int M = SC < THRV ? SC : THRV;

    for (int i = t; i < M; i += 256) {
        float m = gmax[(size_t)i * BQ + q];
        for (int j = i + THRV; j < SC; j += THRV)
            m = fmaxf(m, gmax[(size_t)j * BQ + q]);
        vals[i] = m;
    }
    __syncthreads();

    unsigned prefix = 0, pmask = 0;
    int kneed = KTOP;
    for (int pass = 0; pass < 4; ++pass) {
        const int shift = 24 - pass * 8;
        hist[t] = 0;
        __syncthreads();
        for (int i = t; i < M; i += 256) {
            unsigned k = fkey(vals[i]);
            if ((k & pmask) == prefix) atomicAdd(&hist[(k >> shift) & 255], 1);
        }
        __syncthreads();
        int* src = hist; int* dst = hscan;
        for (int off = 1; off < 256; off <<= 1) {
            int v = src[t] + ((t + off) < 256 ? src[t + off] : 0);
            __syncthreads();
            dst[t] = v;
            __syncthreads();
            int* tmp = src; src = dst; dst = tmp;
        }
        if (src[t] >= kneed && (t == 255 || src[t + 1] < kneed)) {
            bS = t; gtS = (t == 255) ? 0 : src[t + 1];
        }
        __syncthreads();
        kneed -= gtS;
        prefix |= ((unsigned)bS) << shift;
        pmask  |= 0xFFu << shift;
        __syncthreads();
    }
    if (t == 0) thrm[q] = keyval(prefix) - MARGIN;
}

// ---------------------------------------------------------------------------
// select_topk: per query - (B) radix 32nd on bf16 scores; (C) collect all
// within MARGIN below; (D) EXACT fp32 rescore of collected; (E) exact fp32
// radix; (F) collect finalists; (G) 32-round tournament (score desc, idx asc).
// out: [0..B*K) = indices (as float); [B*K..2BK) = scores.
// ---------------------------------------------------------------------------
__global__ __launch_bounds__(256) void select_topk(
    const float* __restrict__ Qf, const float* __restrict__ G,
    const float* __restrict__ cs, const int* __restrict__ ci,
    const int* __restrict__ gcnt,
    const int* __restrict__ ocnt, const int* __restrict__ oq,
    const int* __restrict__ og, const float* __restrict__ osv,
    float* __restrict__ out)
{
    __shared__ int   cnts[NSH];
    __shared__ int   hist[256];
    __shared__ int   hscan[256];
    __shared__ int   Lc[LCCAP];
    __shared__ float Lr[LCCAP];
    __shared__ float Ls[256];
    __shared__ int   Li[256];
    __shared__ int   lcS, lfS, nTotS, bS, gtS;
    __shared__ float wrs[4]; __shared__ int wri[4], wrslot[4];

    const int q = blockIdx.x;
    const int t = threadIdx.x;
    const size_t qbase = (size_t)q * NSH * SCAP;
    const int novf0 = *ocnt;
    const int novf = novf0 < OCAP ? novf0 : OCAP;

    if (t < NSH) {
        int v = gcnt[(q * NSH + t) * 16];
        cnts[t] = v < SCAP ? v : SCAP;
    }
    if (t == 0) nTotS = 0;
    __syncthreads();
    {
        int part = (t < NSH) ? cnts[t] : 0;
        for (int i = t; i < novf; i += 256)
            if (oq[i] == q) part++;
        atomicAdd(&nTotS, part);
    }
    __syncthreads();
    const int nTot = nTotS;

    // (B) radix select: 32nd-largest bf16 score among candidates
    unsigned prefix = 0, pmask = 0;
    int kneed = KTOP;
    if (nTot > KTOP) {
        for (int pass = 0; pass < 4; ++pass) {
            const int shift = 24 - pass * 8;
            hist[t] = 0;
            __syncthreads();
            for (int i = t; i < NSH * SCAP; i += 256) {
                const int sh = i >> 8, sl = i & (SCAP - 1);
                if (sl < cnts[sh]) {
                    unsigned k = fkey(cs[qbase + i]);
                    if ((k & pmask) == prefix)
                        atomicAdd(&hist[(k >> shift) & 255], 1);
                }
            }
            for (int i = t; i < novf; i += 256) {
                if (oq[i] == q) {
                    unsigned k = fkey(osv[i]);
                    if ((k & pmask) == prefix)
                        atomicAdd(&hist[(k >> shift) & 255], 1);
                }
            }
            __syncthreads();
            int* src = hist; int* dst = hscan;
            for (int off = 1; off < 256; off <<= 1) {
                int v = src[t] + ((t + off) < 256 ? src[t + off] : 0);
                __syncthreads();
                dst[t] = v;
                __syncthreads();
                int* tmp = src; src = dst; dst = tmp;
            }
            if (src[t] >= kneed && (t == 255 || src[t + 1] < kneed)) {
                bS = t; gtS = (t == 255) ? 0 : src[t + 1];
            }
            __syncthreads();
            kneed -= gtS;
            prefix |= ((unsigned)bS) << shift;
            pmask  |= 0xFFu << shift;
            __syncthreads();
        }
    }
    const float cutoff = (nTot > KTOP) ? (keyval(prefix) - MARGIN) : NEG_INF;

    // (C) collect candidate indices within margin
    if (t == 0) lcS = 0;
    __syncthreads();
    for (int i = t; i < NSH * SCAP; i += 256) {
        const int sh = i >> 8, sl = i & (SCAP - 1);
        if (sl < cnts[sh]) {
            if (cs[qbase + i] >= cutoff) {
                int p = atomicAdd(&lcS, 1);
                if (p < LCCAP) Lc[p] = ci[qbase + i];
            }
        }
    }
    for (int i = t; i < novf; i += 256) {
        if (oq[i] == q && osv[i] >= cutoff) {
            int p = atomicAdd(&lcS, 1);
            if (p < LCCAP) Lc[p] = og[i];
        }
    }
    __syncthreads();
    const int lc = lcS < LCCAP ? lcS : LCCAP;

    // (D) exact fp32 rescore of collected candidates
    for (int e = t; e < lc; e += 256)
        Lr[e] = dot192(Qf + q * DK, G + (size_t)Lc[e] * DK);
    __syncthreads();

    // (E) exact fp32 radix for the 32nd-largest
    unsigned p2 = 0, m2 = 0;
    kneed = KTOP;
    if (lc > KTOP) {
        for (int pass = 0; pass < 4; ++pass) {
            const int shift = 24 - pass * 8;
            hist[t] = 0;
            __syncthreads();
            for (int e = t; e < lc; e += 256) {
                unsigned k = fkey(Lr[e]);
                if ((k & m2) == p2) atomicAdd(&hist[(k >> shift) & 255], 1);
            }
            __syncthreads();
            int* src = hist; int* dst = hscan;
            for (int off = 1; off < 256; off <<= 1) {
                int v = src[t] + ((t + off) < 256 ? src[t + off] : 0);
                __syncthreads();
                dst[t] = v;
                __syncthreads();
                int* tmp = src; src = dst; dst = tmp;
            }
            if (src[t] >= kneed && (t == 255 || src[t + 1] < kneed)) {
                bS = t; gtS = (t == 255) ? 0 : src[t + 1];
            }
            __syncthreads();
            kneed -= gtS;
            p2 |= ((unsigned)bS) << shift;
            m2 |= 0xFFu << shift;
            __syncthreads();
        }
    }
    const unsigned T2 = (lc > KTOP) ? p2 : 0u;

    // (F) collect finalists (>= exact 32nd key; ties included)
    if (t == 0) lfS = 0;
    __syncthreads();
    for (int e = t; e < lc; e += 256) {
        if (fkey(Lr[e]) >= T2) {
            int p = atomicAdd(&lfS, 1);
            if (p < 256) { Ls[p] = Lr[e]; Li[p] = Lc[e]; }
        }
    }
    __syncthreads();
    const int M = lfS < 256 ? lfS : 256;

    // (G) tournament
    const int w = t >> 6, lane = t & 63;
    for (int r = 0; r < KTOP; ++r) {
        float bv = (t < M) ? Ls[t] : NEG_INF;
        int   bi = (t < M) ? Li[t] : 0x7fffffff;
        int   bslot = t;
        #pragma unroll
        for (int off = 32; off > 0; off >>= 1) {
            float ov = __shfl_xor(bv, off);
            int   oi = __shfl_xor(bi, off);
            int   osl = __shfl_xor(bslot, off);
            if (pri_gt(ov, oi, bv, bi)) { bv = ov; bi = oi; bslot = osl; }
        }
        if (lane == 0) { wrs[w] = bv; wri[w] = bi; wrslot[w] = bslot; }
        __syncthreads();
        if (t == 0) {
            float fv = wrs[0]; int fi = wri[0]; int fs = wrslot[0];
            #pragma unroll
            for (int ww = 1; ww < 4; ++ww)
                if (pri_gt(wrs[ww], wri[ww], fv, fi)) {
                    fv = wrs[ww]; fi = wri[ww]; fs = wrslot[ww];
                }
            out[q * KTOP + r]                     = (float)fi;
            out[(size_t)BQ * KTOP + q * KTOP + r] = fv;
            Ls[fs] = NEG_INF; Li[fs] = 0x7fffffff;
        }
        __syncthreads();
    }
}

// ---------------------------------------------------------------------------
extern "C" void kernel_launch(void* const* d_in, const int* in_sizes, int n_in,
                              void* d_out, int out_size, void* d_ws, size_t ws_size,
                              hipStream_t stream)
{
    const float* Qf   = (const float*)d_in[0];
    const float* G    = (const float*)d_in[1];
    const int*   mask = (const int*)d_in[2];
    const int Ntot = in_sizes[1] / DK;                 // 200000

    const int NCH = (Ntot + CHI - 1) / CHI;            // 6250
    int SC = SCN;                                      // 768 sampled chunks
    if (SC > NCH) SC = NCH;

    // ws layout (bytes): ~18 MB total
    char* w = (char*)d_ws;
    int*   ocnt = (int*)(w + 0);                       // control
    int*   gcnt = (int*)(w + 4096);                    // 8192 ctrs, 64B apart
    const size_t gcnt_bytes = (size_t)BQ * NSH * 16 * 4;   // 512 KB
    size_t off = 4096 + gcnt_bytes;
    float* thrm = (float*)(w + off);  off += 512;
    off = (off + 255) & ~(size_t)255;
    unsigned short* Qi = (unsigned short*)(w + off);   // 48 KB fragment image
    off += (size_t)BQ * DK * 2; off = (off + 255) & ~(size_t)255;
    float* gmax = (float*)(w + off);                   // SC*128*4
    off += (size_t)SC * BQ * 4; off = (off + 255) & ~(size_t)255;
    float* cs   = (float*)(w + off);                   // 128*64*256*4 = 8 MB
    off += (size_t)BQ * NSH * SCAP * 4;
    int*   ci   = (int*)(w + off);                     // 8 MB
    off += (size_t)BQ * NSH * SCAP * 4;
    int*   oqv  = (int*)(w + off);   off += (size_t)OCAP * 4;
    int*   ogv  = (int*)(w + off);   off += (size_t)OCAP * 4;
    float* osv  = (float*)(w + off);

    (void)hipMemsetAsync(w, 0, 4096 + gcnt_bytes, stream);
    qprep<<<dim3(12), dim3(256), 0, stream>>>(Qf, Qi);
    score_pass<0><<<dim3(256), dim3(256), 0, stream>>>(     // sampled maxima
        Qi, G, mask, thrm, gmax, gcnt, cs, ci, ocnt, oqv, ogv, osv,
        Ntot, NCH, SC);
    thr32<<<dim3(BQ), dim3(256), 0, stream>>>(gmax, thrm, SC);
    score_pass<1><<<dim3(GRID1), dim3(256), 0, stream>>>(   // full filter
        Qi, G, mask, thrm, gmax, gcnt, cs, ci, ocnt, oqv, ogv, osv,
        Ntot, NCH, SC);
    select_topk<<<dim3(BQ), dim3(256), 0, stream>>>(
        Qf, G, cs, ci, gcnt, ocnt, oqv, ogv, osv, (float*)d_out);
}